// Round 17
// baseline (40.312 us; speedup 1.0000x reference)
//
#include <hip/hip_runtime.h>
#include <hip/hip_bf16.h>

// PointerNetwork: scores[b,d,e] = sum_h v[h]*tanh(dec_t[b,d,h] + enc_t[b,e,h]),
// out = log_softmax(scores, axis=e).  B=4, DEC=256, ENC=1024, H=256, fp32.
//
// tanh(a+b) = 1 - 2/(1 + e^{2a}e^{2b}).
//   K1 (MFMA bf16 + LDS dbuf): encE = exp2(SC*(x_enc.w1));
//       dec side writes decEi INTERLEAVED [dpair][h][2], PRE-SCALED by 0.5
//       (exp2(x*SC - 1)) for the 8h-merged-rcp overflow control.
//   K2a scores (R16 post-mortem: dur tracks hot-loop instruction count at
//       ~50% issue eff; rcp was 64/136 cy per 16 elems). This round: EIGHT
//       h-terms per rcp (merge two 4-term groups: num=na*db+nb*da, den=da*db)
//       -> 108 cy/16 elems. m' = 0.5 + 0.5 e^{2t} keeps den8 < ~2^40.
//   K2b lsm: in-place row log_softmax on d_out.

#define B_ 4
#define DEC_ 256
#define ENC_ 1024
#define H_ 256

using bf16x8 = __attribute__((ext_vector_type(8))) short;
using f32x4 = __attribute__((ext_vector_type(4))) float;
using f2 = __attribute__((ext_vector_type(2))) float;

__device__ inline short f2bf(float f) {
  union { float f; unsigned u; } x; x.f = f;
  return (short)((x.u + 0x8000u) >> 16);   // round-to-nearest
}

// ---- forced VOP3P packed-f32 helpers (all operands 64-bit pairs) ----
static __device__ __forceinline__ f2 pk_mul(f2 a, f2 b) {
  f2 d; asm("v_pk_mul_f32 %0, %1, %2" : "=v"(d) : "v"(a), "v"(b)); return d;
}
static __device__ __forceinline__ f2 pk_fma(f2 a, f2 b, f2 c) {
  f2 d; asm("v_pk_fma_f32 %0, %1, %2, %3" : "=v"(d) : "v"(a), "v"(b), "v"(c)); return d;
}
// m = dq * bcast(e01.lo) + c   (dq = SGPR pair; e01 = VGPR pair)
static __device__ __forceinline__ f2 pk_fma_dq_elo(f2 dq, f2 e01, f2 c) {
  f2 d; asm("v_pk_fma_f32 %0, %1, %2, %3 op_sel:[0,0,0] op_sel_hi:[1,0,1]"
            : "=v"(d) : "s"(dq), "v"(e01), "v"(c)); return d;
}
// m = dq * bcast(e01.hi) + c
static __device__ __forceinline__ f2 pk_fma_dq_ehi(f2 dq, f2 e01, f2 c) {
  f2 d; asm("v_pk_fma_f32 %0, %1, %2, %3 op_sel:[0,1,0] op_sel_hi:[1,1,1]"
            : "=v"(d) : "s"(dq), "v"(e01), "v"(c)); return d;
}
// t = bcast(w.lo) * m   (w in SGPR pair)
static __device__ __forceinline__ f2 pk_mul_wlo(f2 w, f2 m) {
  f2 d; asm("v_pk_mul_f32 %0, %1, %2 op_sel:[0,0] op_sel_hi:[0,1]"
            : "=v"(d) : "s"(w), "v"(m)); return d;
}
// n = bcast(w.hi) * m + t
static __device__ __forceinline__ f2 pk_fma_whi(f2 w, f2 m, f2 c) {
  f2 d; asm("v_pk_fma_f32 %0, %1, %2, %3 op_sel:[1,0,0] op_sel_hi:[1,1,1]"
            : "=v"(d) : "s"(w), "v"(m), "v"(c)); return d;
}

// ---------------- Kernel 1: dual GEMM (A . B^T) via MFMA + LDS dbuf ----------------
#define LDK 72   // padded row stride in shorts

__global__ __launch_bounds__(256) void gemm_mfma(
    const float* __restrict__ w1, const float* __restrict__ xe,
    const float* __restrict__ xd, const float* __restrict__ w2,
    float* __restrict__ encE, float* __restrict__ decEi) {
  const int blk = blockIdx.x;
  const float* A;
  const float* Bsrc;
  float* C;
  int ldc, m0, n0, decside;
  if (blk < 256) {
    const int b = blk >> 6;
    const int t = blk & 63;            // 4 (h) x 16 (e)
    m0 = (t >> 4) << 6; n0 = (t & 15) << 6;
    A = w1;
    Bsrc = xe + (size_t)b * ENC_ * H_;
    C = encE + (size_t)b * H_ * ENC_;
    ldc = ENC_;
    decside = 0;
  } else {
    const int blk2 = blk - 256;
    const int b = blk2 >> 4;
    const int t = blk2 & 15;           // 4 (d) x 4 (h)
    m0 = (t >> 2) << 6; n0 = (t & 3) << 6;
    A = xd + (size_t)b * DEC_ * H_;
    Bsrc = w2;
    C = decEi + (size_t)b * DEC_ * H_;
    ldc = H_;
    decside = 1;
  }
  const int K = H_;
  const int tid = threadIdx.x;
  const int wave = tid >> 6, lane = tid & 63;
  const int wm = (wave >> 1) << 5, wn = (wave & 1) << 5;
  const int fr = lane & 15;
  const int fk = (lane >> 4) << 3;

  __shared__ short As[2][64][LDK];
  __shared__ short Bs[2][64][LDK];

  const int srow = tid >> 2;
  const int skq = (tid & 3) << 4;
  const float* ag = A + (size_t)(m0 + srow) * K + skq;
  const float* bg = Bsrc + (size_t)(n0 + srow) * K + skq;

  float4 ra[4], rb[4];
#define LDCHUNK(K0)                                                    \
  {                                                                    \
    _Pragma("unroll")                                                  \
    for (int i = 0; i < 4; ++i) {                                      \
      ra[i] = *(const float4*)(ag + (K0) + 4 * i);                     \
      rb[i] = *(const float4*)(bg + (K0) + 4 * i);                     \
    }                                                                  \
  }
#define STCHUNK(BUF)                                                   \
  {                                                                    \
    _Pragma("unroll")                                                  \
    for (int j = 0; j < 2; ++j) {                                      \
      bf16x8 pa, pb;                                                   \
      pa[0] = f2bf(ra[2 * j].x);     pa[1] = f2bf(ra[2 * j].y);        \
      pa[2] = f2bf(ra[2 * j].z);     pa[3] = f2bf(ra[2 * j].w);        \
      pa[4] = f2bf(ra[2 * j + 1].x); pa[5] = f2bf(ra[2 * j + 1].y);    \
      pa[6] = f2bf(ra[2 * j + 1].z); pa[7] = f2bf(ra[2 * j + 1].w);    \
      pb[0] = f2bf(rb[2 * j].x);     pb[1] = f2bf(rb[2 * j].y);        \
      pb[2] = f2bf(rb[2 * j].z);     pb[3] = f2bf(rb[2 * j].w);        \
      pb[4] = f2bf(rb[2 * j + 1].x); pb[5] = f2bf(rb[2 * j + 1].y);    \
      pb[6] = f2bf(rb[2 * j + 1].z); pb[7] = f2bf(rb[2 * j + 1].w);    \
      *(bf16x8*)&As[BUF][srow][skq + 8 * j] = pa;                      \
      *(bf16x8*)&Bs[BUF][srow][skq + 8 * j] = pb;                      \
    }                                                                  \
  }

  f32x4 acc[2][2] = {};

#define COMPUTE(BUF)                                                   \
  {                                                                    \
    _Pragma("unroll")                                                  \
    for (int kk = 0; kk < 2; ++kk) {                                   \
      bf16x8 af[2], bff[2];                                            \
      _Pragma("unroll")                                                \
      for (int mi = 0; mi < 2; ++mi)                                   \
        af[mi] = *(const bf16x8*)&As[BUF][wm + (mi << 4) + fr][(kk << 5) + fk]; \
      _Pragma("unroll")                                                \
      for (int ni = 0; ni < 2; ++ni)                                   \
        bff[ni] = *(const bf16x8*)&Bs[BUF][wn + (ni << 4) + fr][(kk << 5) + fk]; \
      _Pragma("unroll")                                                \
      for (int mi = 0; mi < 2; ++mi)                                   \
        _Pragma("unroll")                                              \
        for (int ni = 0; ni < 2; ++ni)                                 \
          acc[mi][ni] = __builtin_amdgcn_mfma_f32_16x16x32_bf16(       \
              af[mi], bff[ni], acc[mi][ni], 0, 0, 0);                  \
    }                                                                  \
  }

  LDCHUNK(0)
  STCHUNK(0)
  __syncthreads();
  LDCHUNK(64) COMPUTE(0) STCHUNK(1) __syncthreads();
  LDCHUNK(128) COMPUTE(1) STCHUNK(0) __syncthreads();
  LDCHUNK(192) COMPUTE(0) STCHUNK(1) __syncthreads();
  COMPUTE(1)

  const float SC = 2.8853900817779268f;  // 2*log2(e)
  const float off = decside ? 1.0f : 0.0f;  // dec: store 0.5*exp2 = exp2(x-1)
#pragma unroll
  for (int mi = 0; mi < 2; ++mi) {
#pragma unroll
    for (int ni = 0; ni < 2; ++ni) {
      const int row = m0 + wm + (mi << 4) + ((lane >> 4) << 2);
      const int col = n0 + wn + (ni << 4) + (lane & 15);
#pragma unroll
      for (int r = 0; r < 4; ++r) {
        const float val = __builtin_amdgcn_exp2f(acc[mi][ni][r] * SC - off);
        if (decside) {
          // interleaved: [(d>>1)][h][d&1]
          const int rr = row + r;
          C[((size_t)(rr >> 1) * H_ + col) * 2 + (rr & 1)] = val;
        } else {
          C[(size_t)(row + r) * ldc + col] = val;
        }
      }
    }
  }
}

// ---------------- Kernel 2a: raw scores (8h per rcp, h-major LDS, VOP3P) ----------------
// Block = 1024 thr = 16 waves, covers 64 e x 32 d. Es = [h(256)][e(64)] fp32
// (64KB, conflict-free b32 reads). Wave w owns d-pair via interleaved decEi'
// (= 0.5*decE). m' = dq'*E + 0.5; per 8h bundle: two 4-term groups merged
// into ONE rcp pair: 8 ds + 30 pk + 2 rcp. Writes raw -acc. Grid 512.

__global__ __launch_bounds__(1024) void scores_k(
    const float* __restrict__ encE, const float* __restrict__ decEi,
    const float* __restrict__ v, float* __restrict__ out) {
  const int bid = blockIdx.x;            // 0..511
  // XCD pinning: batch b -> XCDs {2b, 2b+1}
  const int xcd = bid & 7;
  const int b = xcd >> 1;
  const int rem = ((bid >> 3) << 1) | (xcd & 1);   // 0..127 within batch
  const int es = rem & 15;               // e-slice (64 e)
  const int d0 = (rem >> 4) << 5;        // d-group of 32
  const int tid = threadIdx.x;
  const int lane = tid & 63;
  const int wid = __builtin_amdgcn_readfirstlane(tid >> 6);  // 0..15

  __shared__ __align__(16) float Es[H_ * 64];    // [h][e] h-major, 64KB

  const int e0 = es << 6;
  const float* egbase = encE + (size_t)b * H_ * ENC_ + e0;

  // ---- stage (direct copy): 4 x {float4 load + ds_write_b128} / thread ----
#pragma unroll
  for (int s = 0; s < 4; ++s) {
    const int fi = (s << 10) + tid;      // 0..4095
    const int h = fi >> 4;               // 0..255
    const int c = fi & 15;               // float4 chunk along e
    const float4 x = *(const float4*)(egbase + (size_t)h * ENC_ + (c << 2));
    *(float4*)&Es[(h << 6) + (c << 2)] = x;
  }
  __syncthreads();

  const int dpair = (d0 >> 1) + wid;     // d = 2*dpair, 2*dpair+1
  const float* dpi = decEi + (size_t)b * DEC_ * H_ + (size_t)dpair * (2 * H_);
  const float* epl = Es + lane;

  f2 acc = {0.0f, 0.0f};
  const f2 half2 = {0.5f, 0.5f};

#pragma unroll 2
  for (int gg = 0; gg < 32; ++gg) {      // 8 h per iteration
    const int h8 = gg << 3;
    // conflict-free b32 reads; pack adjacent h into register pairs
    f2 E01, E23, E45, E67;
    E01.x = epl[(h8 + 0) << 6]; E01.y = epl[(h8 + 1) << 6];
    E23.x = epl[(h8 + 2) << 6]; E23.y = epl[(h8 + 3) << 6];
    E45.x = epl[(h8 + 4) << 6]; E45.y = epl[(h8 + 5) << 6];
    E67.x = epl[(h8 + 6) << 6]; E67.y = epl[(h8 + 7) << 6];
    const float* dg = dpi + (h8 << 1);   // uniform -> SGPR pairs
    const f2 dq0 = *(const f2*)(dg);
    const f2 dq1 = *(const f2*)(dg + 2);
    const f2 dq2 = *(const f2*)(dg + 4);
    const f2 dq3 = *(const f2*)(dg + 6);
    const f2 dq4 = *(const f2*)(dg + 8);
    const f2 dq5 = *(const f2*)(dg + 10);
    const f2 dq6 = *(const f2*)(dg + 12);
    const f2 dq7 = *(const f2*)(dg + 14);
    const f2 w01 = *(const f2*)(v + h8);
    const f2 w23 = *(const f2*)(v + h8 + 2);
    const f2 w45 = *(const f2*)(v + h8 + 4);
    const f2 w67 = *(const f2*)(v + h8 + 6);

    // group a: h8..h8+3
    const f2 ma0 = pk_fma_dq_elo(dq0, E01, half2);
    const f2 ma1 = pk_fma_dq_ehi(dq1, E01, half2);
    const f2 ma2 = pk_fma_dq_elo(dq2, E23, half2);
    const f2 ma3 = pk_fma_dq_ehi(dq3, E23, half2);
    const f2 paa = pk_mul(ma0, ma1);
    const f2 pab = pk_mul(ma2, ma3);
    const f2 na01 = pk_fma_whi(w01, ma0, pk_mul_wlo(w01, ma1));
    const f2 na23 = pk_fma_whi(w23, ma2, pk_mul_wlo(w23, ma3));
    const f2 numa = pk_fma(na01, pab, pk_mul(na23, paa));
    const f2 dena = pk_mul(paa, pab);
    // group b: h8+4..h8+7
    const f2 mb0 = pk_fma_dq_elo(dq4, E45, half2);
    const f2 mb1 = pk_fma_dq_ehi(dq5, E45, half2);
    const f2 mb2 = pk_fma_dq_elo(dq6, E67, half2);
    const f2 mb3 = pk_fma_dq_ehi(dq7, E67, half2);
    const f2 pba = pk_mul(mb0, mb1);
    const f2 pbb = pk_mul(mb2, mb3);
    const f2 nb01 = pk_fma_whi(w45, mb0, pk_mul_wlo(w45, mb1));
    const f2 nb23 = pk_fma_whi(w67, mb2, pk_mul_wlo(w67, mb3));
    const f2 numb = pk_fma(nb01, pbb, pk_mul(nb23, pba));
    const f2 denb = pk_mul(pba, pbb);
    // merge: one rcp pair per 8 h
    const f2 num = pk_fma(numa, denb, pk_mul(numb, dena));
    const f2 den = pk_mul(dena, denb);
    f2 r;
    r.x = __builtin_amdgcn_rcpf(den.x);
    r.y = __builtin_amdgcn_rcpf(den.y);
    acc = pk_fma(num, r, acc);
  }

  const int d = dpair << 1;
  float* orow = out + (size_t)(b * DEC_ + d) * ENC_ + e0 + lane;
  orow[0] = -acc.x;         // 0.5 prescale folds the old -2 into -1
  orow[ENC_] = -acc.y;
}

// ---------------- Kernel 2b: in-place row log_softmax ----------------
// 1 row (1024 f32) per block, 256 thr x float4.

__global__ __launch_bounds__(256) void lsm_k(float* __restrict__ out) {
  const int row = blockIdx.x;            // 0..1023
  float* p = out + (size_t)row * ENC_;
  const int tid = threadIdx.x;
  const int lane = tid & 63, wid = tid >> 6;

  __shared__ float rm[4], rs[4];

  float4 x = *(const float4*)(p + 4 * tid);

  float m = fmaxf(fmaxf(x.x, x.y), fmaxf(x.z, x.w));
#pragma unroll
  for (int o = 32; o >= 1; o >>= 1) m = fmaxf(m, __shfl_xor(m, o, 64));
  if (lane == 0) rm[wid] = m;
  __syncthreads();
  const float M = fmaxf(fmaxf(rm[0], rm[1]), fmaxf(rm[2], rm[3]));

  const float L2E = 1.4426950408889634f;
  const float LN2 = 0.6931471805599453f;
  float z = __builtin_amdgcn_exp2f((x.x - M) * L2E) +
            __builtin_amdgcn_exp2f((x.y - M) * L2E) +
            __builtin_amdgcn_exp2f((x.z - M) * L2E) +
            __builtin_amdgcn_exp2f((x.w - M) * L2E);
#pragma unroll
  for (int o = 32; o >= 1; o >>= 1) z += __shfl_xor(z, o, 64);
  if (lane == 0) rs[wid] = z;
  __syncthreads();
  const float S = (rs[0] + rs[1]) + (rs[2] + rs[3]);

  const float lse = M + LN2 * __builtin_amdgcn_logf(S);
  x.x -= lse; x.y -= lse; x.z -= lse; x.w -= lse;
  *(float4*)(p + 4 * tid) = x;
}

extern "C" void kernel_launch(void* const* d_in, const int* in_sizes, int n_in,
                              void* d_out, int out_size, void* d_ws, size_t ws_size,
                              hipStream_t stream) {
  const float* xd = (const float*)d_in[0];  // (4,256,256)
  const float* xe = (const float*)d_in[1];  // (4,1024,256)
  const float* w1 = (const float*)d_in[2];  // (256,256)
  const float* w2 = (const float*)d_in[3];  // (256,256)
  const float* v  = (const float*)d_in[4];  // (256,)
  float* out = (float*)d_out;               // (4,256,1024)

  float* encE = (float*)d_ws;                          // 4 MB: [B][H][ENC]
  float* decEi = encE + (size_t)B_ * H_ * ENC_;        // 1 MB: [B][dpair][H][2], 0.5-scaled

  gemm_mfma<<<320, 256, 0, stream>>>(w1, xe, xd, w2, encE, decEi);
  scores_k<<<512, 1024, 0, stream>>>(encE, decEi, v, out);
  lsm_k<<<B_ * DEC_, 256, 0, stream>>>(out);
}

// Round 18
// 40.257 us; speedup vs baseline: 1.0014x; 1.0014x over previous
//
#include <hip/hip_runtime.h>
#include <hip/hip_bf16.h>

// PointerNetwork: scores[b,d,e] = sum_h v[h]*tanh(dec_t[b,d,h] + enc_t[b,e,h]),
// out = log_softmax(scores, axis=e).  B=4, DEC=256, ENC=1024, H=256, fp32.
//
// tanh(a+b) = 1 - 2/(1 + e^{2a}e^{2b}).
//   K1 (MFMA bf16 + LDS dbuf): encE = exp2(SC*(x_enc.w1));
//       dec side writes decEi INTERLEAVED [dpair][h][2].
//   K2a scores (R17 post-mortem: rcp was overlapped/free; pk-VALU issue is
//       the bound and pk_f32 = ~4cy (157.3 = 2x78.6 packed rate)). R16
//       structure + d-QUAD per wave: each E read/pack/loop-iter serves 4 d
//       (2 packed acc pairs), halving non-pk overhead per element.
//   K2b lsm: in-place row log_softmax on d_out.

#define B_ 4
#define DEC_ 256
#define ENC_ 1024
#define H_ 256

using bf16x8 = __attribute__((ext_vector_type(8))) short;
using f32x4 = __attribute__((ext_vector_type(4))) float;
using f2 = __attribute__((ext_vector_type(2))) float;

__device__ inline short f2bf(float f) {
  union { float f; unsigned u; } x; x.f = f;
  return (short)((x.u + 0x8000u) >> 16);   // round-to-nearest
}

// ---- forced VOP3P packed-f32 helpers (all operands 64-bit pairs) ----
static __device__ __forceinline__ f2 pk_mul(f2 a, f2 b) {
  f2 d; asm("v_pk_mul_f32 %0, %1, %2" : "=v"(d) : "v"(a), "v"(b)); return d;
}
static __device__ __forceinline__ f2 pk_fma(f2 a, f2 b, f2 c) {
  f2 d; asm("v_pk_fma_f32 %0, %1, %2, %3" : "=v"(d) : "v"(a), "v"(b), "v"(c)); return d;
}
// m = dq * bcast(e01.lo) + c   (dq = SGPR pair; e01 = VGPR pair)
static __device__ __forceinline__ f2 pk_fma_dq_elo(f2 dq, f2 e01, f2 c) {
  f2 d; asm("v_pk_fma_f32 %0, %1, %2, %3 op_sel:[0,0,0] op_sel_hi:[1,0,1]"
            : "=v"(d) : "s"(dq), "v"(e01), "v"(c)); return d;
}
// m = dq * bcast(e01.hi) + c
static __device__ __forceinline__ f2 pk_fma_dq_ehi(f2 dq, f2 e01, f2 c) {
  f2 d; asm("v_pk_fma_f32 %0, %1, %2, %3 op_sel:[0,1,0] op_sel_hi:[1,1,1]"
            : "=v"(d) : "s"(dq), "v"(e01), "v"(c)); return d;
}
// t = bcast(w.lo) * m   (w in SGPR pair)
static __device__ __forceinline__ f2 pk_mul_wlo(f2 w, f2 m) {
  f2 d; asm("v_pk_mul_f32 %0, %1, %2 op_sel:[0,0] op_sel_hi:[0,1]"
            : "=v"(d) : "s"(w), "v"(m)); return d;
}
// n = bcast(w.hi) * m + t
static __device__ __forceinline__ f2 pk_fma_whi(f2 w, f2 m, f2 c) {
  f2 d; asm("v_pk_fma_f32 %0, %1, %2, %3 op_sel:[1,0,0] op_sel_hi:[1,1,1]"
            : "=v"(d) : "s"(w), "v"(m), "v"(c)); return d;
}

// ---------------- Kernel 1: dual GEMM (A . B^T) via MFMA + LDS dbuf ----------------
#define LDK 72   // padded row stride in shorts

__global__ __launch_bounds__(256) void gemm_mfma(
    const float* __restrict__ w1, const float* __restrict__ xe,
    const float* __restrict__ xd, const float* __restrict__ w2,
    float* __restrict__ encE, float* __restrict__ decEi) {
  const int blk = blockIdx.x;
  const float* A;
  const float* Bsrc;
  float* C;
  int ldc, m0, n0, decside;
  if (blk < 256) {
    const int b = blk >> 6;
    const int t = blk & 63;            // 4 (h) x 16 (e)
    m0 = (t >> 4) << 6; n0 = (t & 15) << 6;
    A = w1;
    Bsrc = xe + (size_t)b * ENC_ * H_;
    C = encE + (size_t)b * H_ * ENC_;
    ldc = ENC_;
    decside = 0;
  } else {
    const int blk2 = blk - 256;
    const int b = blk2 >> 4;
    const int t = blk2 & 15;           // 4 (d) x 4 (h)
    m0 = (t >> 2) << 6; n0 = (t & 3) << 6;
    A = xd + (size_t)b * DEC_ * H_;
    Bsrc = w2;
    C = decEi + (size_t)b * DEC_ * H_;
    ldc = H_;
    decside = 1;
  }
  const int K = H_;
  const int tid = threadIdx.x;
  const int wave = tid >> 6, lane = tid & 63;
  const int wm = (wave >> 1) << 5, wn = (wave & 1) << 5;
  const int fr = lane & 15;
  const int fk = (lane >> 4) << 3;

  __shared__ short As[2][64][LDK];
  __shared__ short Bs[2][64][LDK];

  const int srow = tid >> 2;
  const int skq = (tid & 3) << 4;
  const float* ag = A + (size_t)(m0 + srow) * K + skq;
  const float* bg = Bsrc + (size_t)(n0 + srow) * K + skq;

  float4 ra[4], rb[4];
#define LDCHUNK(K0)                                                    \
  {                                                                    \
    _Pragma("unroll")                                                  \
    for (int i = 0; i < 4; ++i) {                                      \
      ra[i] = *(const float4*)(ag + (K0) + 4 * i);                     \
      rb[i] = *(const float4*)(bg + (K0) + 4 * i);                     \
    }                                                                  \
  }
#define STCHUNK(BUF)                                                   \
  {                                                                    \
    _Pragma("unroll")                                                  \
    for (int j = 0; j < 2; ++j) {                                      \
      bf16x8 pa, pb;                                                   \
      pa[0] = f2bf(ra[2 * j].x);     pa[1] = f2bf(ra[2 * j].y);        \
      pa[2] = f2bf(ra[2 * j].z);     pa[3] = f2bf(ra[2 * j].w);        \
      pa[4] = f2bf(ra[2 * j + 1].x); pa[5] = f2bf(ra[2 * j + 1].y);    \
      pa[6] = f2bf(ra[2 * j + 1].z); pa[7] = f2bf(ra[2 * j + 1].w);    \
      pb[0] = f2bf(rb[2 * j].x);     pb[1] = f2bf(rb[2 * j].y);        \
      pb[2] = f2bf(rb[2 * j].z);     pb[3] = f2bf(rb[2 * j].w);        \
      pb[4] = f2bf(rb[2 * j + 1].x); pb[5] = f2bf(rb[2 * j + 1].y);    \
      pb[6] = f2bf(rb[2 * j + 1].z); pb[7] = f2bf(rb[2 * j + 1].w);    \
      *(bf16x8*)&As[BUF][srow][skq + 8 * j] = pa;                      \
      *(bf16x8*)&Bs[BUF][srow][skq + 8 * j] = pb;                      \
    }                                                                  \
  }

  f32x4 acc[2][2] = {};

#define COMPUTE(BUF)                                                   \
  {                                                                    \
    _Pragma("unroll")                                                  \
    for (int kk = 0; kk < 2; ++kk) {                                   \
      bf16x8 af[2], bff[2];                                            \
      _Pragma("unroll")                                                \
      for (int mi = 0; mi < 2; ++mi)                                   \
        af[mi] = *(const bf16x8*)&As[BUF][wm + (mi << 4) + fr][(kk << 5) + fk]; \
      _Pragma("unroll")                                                \
      for (int ni = 0; ni < 2; ++ni)                                   \
        bff[ni] = *(const bf16x8*)&Bs[BUF][wn + (ni << 4) + fr][(kk << 5) + fk]; \
      _Pragma("unroll")                                                \
      for (int mi = 0; mi < 2; ++mi)                                   \
        _Pragma("unroll")                                              \
        for (int ni = 0; ni < 2; ++ni)                                 \
          acc[mi][ni] = __builtin_amdgcn_mfma_f32_16x16x32_bf16(       \
              af[mi], bff[ni], acc[mi][ni], 0, 0, 0);                  \
    }                                                                  \
  }

  LDCHUNK(0)
  STCHUNK(0)
  __syncthreads();
  LDCHUNK(64) COMPUTE(0) STCHUNK(1) __syncthreads();
  LDCHUNK(128) COMPUTE(1) STCHUNK(0) __syncthreads();
  LDCHUNK(192) COMPUTE(0) STCHUNK(1) __syncthreads();
  COMPUTE(1)

  const float SC = 2.8853900817779268f;  // 2*log2(e)
#pragma unroll
  for (int mi = 0; mi < 2; ++mi) {
#pragma unroll
    for (int ni = 0; ni < 2; ++ni) {
      const int row = m0 + wm + (mi << 4) + ((lane >> 4) << 2);
      const int col = n0 + wn + (ni << 4) + (lane & 15);
#pragma unroll
      for (int r = 0; r < 4; ++r) {
        const float val = __builtin_amdgcn_exp2f(acc[mi][ni][r] * SC);
        if (decside) {
          // interleaved: [(d>>1)][h][d&1]
          const int rr = row + r;
          C[((size_t)(rr >> 1) * H_ + col) * 2 + (rr & 1)] = val;
        } else {
          C[(size_t)(row + r) * ldc + col] = val;
        }
      }
    }
  }
}

// ---------------- Kernel 2a: raw scores (d-QUAD per wave, h-major LDS, VOP3P) ----------------
// Block = 512 thr = 8 waves, covers 64 e x 32 d. Es = [h(256)][e(64)] fp32
// (64KB, conflict-free b32 reads, direct-copy staging). Wave w owns TWO
// consecutive d-pairs (4 d): E reads/packing/loop overhead amortized over
// 4 d instead of 2; pk-op count per element unchanged. dq/w = SGPR pairs.
// Writes raw -2*acc. Grid 512 -> 2 blk/CU, 8 waves/SIMD.

__global__ __launch_bounds__(512) void scores_k(
    const float* __restrict__ encE, const float* __restrict__ decEi,
    const float* __restrict__ v, float* __restrict__ out) {
  const int bid = blockIdx.x;            // 0..511
  // XCD pinning: batch b -> XCDs {2b, 2b+1}
  const int xcd = bid & 7;
  const int b = xcd >> 1;
  const int rem = ((bid >> 3) << 1) | (xcd & 1);   // 0..127 within batch
  const int es = rem & 15;               // e-slice (64 e)
  const int d0 = (rem >> 4) << 5;        // d-group of 32
  const int tid = threadIdx.x;
  const int lane = tid & 63;
  const int wid = __builtin_amdgcn_readfirstlane(tid >> 6);  // 0..7

  __shared__ __align__(16) float Es[H_ * 64];    // [h][e] h-major, 64KB

  const int e0 = es << 6;
  const float* egbase = encE + (size_t)b * H_ * ENC_ + e0;

  // ---- stage (direct copy): 8 x {float4 load + ds_write_b128} / thread ----
#pragma unroll
  for (int s = 0; s < 8; ++s) {
    const int fi = (s << 9) + tid;       // 0..4095
    const int h = fi >> 4;               // 0..255
    const int c = fi & 15;               // float4 chunk along e
    const float4 x = *(const float4*)(egbase + (size_t)h * ENC_ + (c << 2));
    *(float4*)&Es[(h << 6) + (c << 2)] = x;
  }
  __syncthreads();

  // wave owns d-pairs {dp, dp+1} -> d = d0+4w .. d0+4w+3
  const int dp = (d0 >> 1) + (wid << 1);
  const float* dpi = decEi + (size_t)b * DEC_ * H_ + (size_t)dp * (2 * H_);
  const float* epl = Es + lane;

  f2 acc0 = {0.0f, 0.0f};
  f2 acc1 = {0.0f, 0.0f};
  const f2 one2 = {1.0f, 1.0f};

#define BUNDLE4(DQB, E01, E23, W01, W23, ACC)                          \
  {                                                                    \
    const f2 dq0 = *(const f2*)((DQB));                                \
    const f2 dq1 = *(const f2*)((DQB) + 2);                            \
    const f2 dq2 = *(const f2*)((DQB) + 4);                            \
    const f2 dq3 = *(const f2*)((DQB) + 6);                            \
    const f2 m0 = pk_fma_dq_elo(dq0, E01, one2);                       \
    const f2 m1 = pk_fma_dq_ehi(dq1, E01, one2);                       \
    const f2 m2 = pk_fma_dq_elo(dq2, E23, one2);                       \
    const f2 m3 = pk_fma_dq_ehi(dq3, E23, one2);                       \
    const f2 pa = pk_mul(m0, m1);                                      \
    const f2 pb = pk_mul(m2, m3);                                      \
    const f2 n01 = pk_fma_whi(W01, m0, pk_mul_wlo(W01, m1));           \
    const f2 n23 = pk_fma_whi(W23, m2, pk_mul_wlo(W23, m3));           \
    const f2 num = pk_fma(n01, pb, pk_mul(n23, pa));                   \
    const f2 den = pk_mul(pa, pb);                                     \
    f2 r;                                                              \
    r.x = __builtin_amdgcn_rcpf(den.x);                                \
    r.y = __builtin_amdgcn_rcpf(den.y);                                \
    ACC = pk_fma(num, r, ACC);                                         \
  }

#pragma unroll 4
  for (int g = 0; g < 64; ++g) {
    // conflict-free b32 reads; pack adjacent h into register pairs (shared by 4 d)
    f2 E01, E23;
    E01.x = epl[(4 * g + 0) << 6];
    E01.y = epl[(4 * g + 1) << 6];
    E23.x = epl[(4 * g + 2) << 6];
    E23.y = epl[(4 * g + 3) << 6];
    const f2 w01 = *(const f2*)(v + (g << 2));     // uniform -> SGPR pair
    const f2 w23 = *(const f2*)(v + (g << 2) + 2);
    BUNDLE4(dpi + (g << 3), E01, E23, w01, w23, acc0)            // pair dp
    BUNDLE4(dpi + 2 * H_ + (g << 3), E01, E23, w01, w23, acc1)   // pair dp+1
  }

  const int d = d0 + (wid << 2);
  float* orow = out + (size_t)(b * DEC_ + d) * ENC_ + e0 + lane;
  orow[0] = -2.0f * acc0.x;
  orow[ENC_] = -2.0f * acc0.y;
  orow[2 * ENC_] = -2.0f * acc1.x;
  orow[3 * ENC_] = -2.0f * acc1.y;
}

// ---------------- Kernel 2b: in-place row log_softmax ----------------
// 1 row (1024 f32) per block, 256 thr x float4.

__global__ __launch_bounds__(256) void lsm_k(float* __restrict__ out) {
  const int row = blockIdx.x;            // 0..1023
  float* p = out + (size_t)row * ENC_;
  const int tid = threadIdx.x;
  const int lane = tid & 63, wid = tid >> 6;

  __shared__ float rm[4], rs[4];

  float4 x = *(const float4*)(p + 4 * tid);

  float m = fmaxf(fmaxf(x.x, x.y), fmaxf(x.z, x.w));
#pragma unroll
  for (int o = 32; o >= 1; o >>= 1) m = fmaxf(m, __shfl_xor(m, o, 64));
  if (lane == 0) rm[wid] = m;
  __syncthreads();
  const float M = fmaxf(fmaxf(rm[0], rm[1]), fmaxf(rm[2], rm[3]));

  const float L2E = 1.4426950408889634f;
  const float LN2 = 0.6931471805599453f;
  float z = __builtin_amdgcn_exp2f((x.x - M) * L2E) +
            __builtin_amdgcn_exp2f((x.y - M) * L2E) +
            __builtin_amdgcn_exp2f((x.z - M) * L2E) +
            __builtin_amdgcn_exp2f((x.w - M) * L2E);
#pragma unroll
  for (int o = 32; o >= 1; o >>= 1) z += __shfl_xor(z, o, 64);
  if (lane == 0) rs[wid] = z;
  __syncthreads();
  const float S = (rs[0] + rs[1]) + (rs[2] + rs[3]);

  const float lse = M + LN2 * __builtin_amdgcn_logf(S);
  x.x -= lse; x.y -= lse; x.z -= lse; x.w -= lse;
  *(float4*)(p + 4 * tid) = x;
}

extern "C" void kernel_launch(void* const* d_in, const int* in_sizes, int n_in,
                              void* d_out, int out_size, void* d_ws, size_t ws_size,
                              hipStream_t stream) {
  const float* xd = (const float*)d_in[0];  // (4,256,256)
  const float* xe = (const float*)d_in[1];  // (4,1024,256)
  const float* w1 = (const float*)d_in[2];  // (256,256)
  const float* w2 = (const float*)d_in[3];  // (256,256)
  const float* v  = (const float*)d_in[4];  // (256,)
  float* out = (float*)d_out;               // (4,256,1024)

  float* encE = (float*)d_ws;                          // 4 MB: [B][H][ENC]
  float* decEi = encE + (size_t)B_ * H_ * ENC_;        // 1 MB: [B][dpair][H][2]

  gemm_mfma<<<320, 256, 0, stream>>>(w1, xe, xd, w2, encE, decEi);
  scores_k<<<512, 512, 0, stream>>>(encE, decEi, v, out);
  lsm_k<<<B_ * DEC_, 256, 0, stream>>>(out);
}

// Round 19
// 39.622 us; speedup vs baseline: 1.0174x; 1.0160x over previous
//
#include <hip/hip_runtime.h>
#include <hip/hip_bf16.h>

// PointerNetwork: scores[b,d,e] = sum_h v[h]*tanh(dec_t[b,d,h] + enc_t[b,e,h]),
// out = log_softmax(scores, axis=e).  B=4, DEC=256, ENC=1024, H=256, fp32.
//
// tanh(a+b) = 1 - 2/(1 + e^{2a}e^{2b}).
//   K1 (MFMA bf16 + LDS dbuf): encE = exp2(SC*(x_enc.w1));
//       dec side writes decEi INTERLEAVED [dpair][h][2].
//   K2a scores: R16 EXACT REVERT (best measured, 39.4us total). h-major Es
//       [h][64e] -> conflict-free ds_read; forced VOP3P d-pair bundle
//       (14 pk + 2 rcp per 8 elems); dq/w = SGPR pairs. R17 (8h/rcp merge)
//       and R18 (d-quad) both regressed -> scores_k is at its source-level
//       scheduling optimum (~50% VALU issue eff across 10 variants).
//   K2b lsm: in-place row log_softmax on d_out.

#define B_ 4
#define DEC_ 256
#define ENC_ 1024
#define H_ 256

using bf16x8 = __attribute__((ext_vector_type(8))) short;
using f32x4 = __attribute__((ext_vector_type(4))) float;
using f2 = __attribute__((ext_vector_type(2))) float;

__device__ inline short f2bf(float f) {
  union { float f; unsigned u; } x; x.f = f;
  return (short)((x.u + 0x8000u) >> 16);   // round-to-nearest
}

// ---- forced VOP3P packed-f32 helpers (all operands 64-bit pairs) ----
static __device__ __forceinline__ f2 pk_mul(f2 a, f2 b) {
  f2 d; asm("v_pk_mul_f32 %0, %1, %2" : "=v"(d) : "v"(a), "v"(b)); return d;
}
static __device__ __forceinline__ f2 pk_fma(f2 a, f2 b, f2 c) {
  f2 d; asm("v_pk_fma_f32 %0, %1, %2, %3" : "=v"(d) : "v"(a), "v"(b), "v"(c)); return d;
}
// m = dq * bcast(e01.lo) + c   (dq = SGPR pair; e01 = VGPR pair)
static __device__ __forceinline__ f2 pk_fma_dq_elo(f2 dq, f2 e01, f2 c) {
  f2 d; asm("v_pk_fma_f32 %0, %1, %2, %3 op_sel:[0,0,0] op_sel_hi:[1,0,1]"
            : "=v"(d) : "s"(dq), "v"(e01), "v"(c)); return d;
}
// m = dq * bcast(e01.hi) + c
static __device__ __forceinline__ f2 pk_fma_dq_ehi(f2 dq, f2 e01, f2 c) {
  f2 d; asm("v_pk_fma_f32 %0, %1, %2, %3 op_sel:[0,1,0] op_sel_hi:[1,1,1]"
            : "=v"(d) : "s"(dq), "v"(e01), "v"(c)); return d;
}
// t = bcast(w.lo) * m   (w in SGPR pair)
static __device__ __forceinline__ f2 pk_mul_wlo(f2 w, f2 m) {
  f2 d; asm("v_pk_mul_f32 %0, %1, %2 op_sel:[0,0] op_sel_hi:[0,1]"
            : "=v"(d) : "s"(w), "v"(m)); return d;
}
// n = bcast(w.hi) * m + t
static __device__ __forceinline__ f2 pk_fma_whi(f2 w, f2 m, f2 c) {
  f2 d; asm("v_pk_fma_f32 %0, %1, %2, %3 op_sel:[1,0,0] op_sel_hi:[1,1,1]"
            : "=v"(d) : "s"(w), "v"(m), "v"(c)); return d;
}

// ---------------- Kernel 1: dual GEMM (A . B^T) via MFMA + LDS dbuf ----------------
#define LDK 72   // padded row stride in shorts

__global__ __launch_bounds__(256) void gemm_mfma(
    const float* __restrict__ w1, const float* __restrict__ xe,
    const float* __restrict__ xd, const float* __restrict__ w2,
    float* __restrict__ encE, float* __restrict__ decEi) {
  const int blk = blockIdx.x;
  const float* A;
  const float* Bsrc;
  float* C;
  int ldc, m0, n0, decside;
  if (blk < 256) {
    const int b = blk >> 6;
    const int t = blk & 63;            // 4 (h) x 16 (e)
    m0 = (t >> 4) << 6; n0 = (t & 15) << 6;
    A = w1;
    Bsrc = xe + (size_t)b * ENC_ * H_;
    C = encE + (size_t)b * H_ * ENC_;
    ldc = ENC_;
    decside = 0;
  } else {
    const int blk2 = blk - 256;
    const int b = blk2 >> 4;
    const int t = blk2 & 15;           // 4 (d) x 4 (h)
    m0 = (t >> 2) << 6; n0 = (t & 3) << 6;
    A = xd + (size_t)b * DEC_ * H_;
    Bsrc = w2;
    C = decEi + (size_t)b * DEC_ * H_;
    ldc = H_;
    decside = 1;
  }
  const int K = H_;
  const int tid = threadIdx.x;
  const int wave = tid >> 6, lane = tid & 63;
  const int wm = (wave >> 1) << 5, wn = (wave & 1) << 5;
  const int fr = lane & 15;
  const int fk = (lane >> 4) << 3;

  __shared__ short As[2][64][LDK];
  __shared__ short Bs[2][64][LDK];

  const int srow = tid >> 2;
  const int skq = (tid & 3) << 4;
  const float* ag = A + (size_t)(m0 + srow) * K + skq;
  const float* bg = Bsrc + (size_t)(n0 + srow) * K + skq;

  float4 ra[4], rb[4];
#define LDCHUNK(K0)                                                    \
  {                                                                    \
    _Pragma("unroll")                                                  \
    for (int i = 0; i < 4; ++i) {                                      \
      ra[i] = *(const float4*)(ag + (K0) + 4 * i);                     \
      rb[i] = *(const float4*)(bg + (K0) + 4 * i);                     \
    }                                                                  \
  }
#define STCHUNK(BUF)                                                   \
  {                                                                    \
    _Pragma("unroll")                                                  \
    for (int j = 0; j < 2; ++j) {                                      \
      bf16x8 pa, pb;                                                   \
      pa[0] = f2bf(ra[2 * j].x);     pa[1] = f2bf(ra[2 * j].y);        \
      pa[2] = f2bf(ra[2 * j].z);     pa[3] = f2bf(ra[2 * j].w);        \
      pa[4] = f2bf(ra[2 * j + 1].x); pa[5] = f2bf(ra[2 * j + 1].y);    \
      pa[6] = f2bf(ra[2 * j + 1].z); pa[7] = f2bf(ra[2 * j + 1].w);    \
      pb[0] = f2bf(rb[2 * j].x);     pb[1] = f2bf(rb[2 * j].y);        \
      pb[2] = f2bf(rb[2 * j].z);     pb[3] = f2bf(rb[2 * j].w);        \
      pb[4] = f2bf(rb[2 * j + 1].x); pb[5] = f2bf(rb[2 * j + 1].y);    \
      pb[6] = f2bf(rb[2 * j + 1].z); pb[7] = f2bf(rb[2 * j + 1].w);    \
      *(bf16x8*)&As[BUF][srow][skq + 8 * j] = pa;                      \
      *(bf16x8*)&Bs[BUF][srow][skq + 8 * j] = pb;                      \
    }                                                                  \
  }

  f32x4 acc[2][2] = {};

#define COMPUTE(BUF)                                                   \
  {                                                                    \
    _Pragma("unroll")                                                  \
    for (int kk = 0; kk < 2; ++kk) {                                   \
      bf16x8 af[2], bff[2];                                            \
      _Pragma("unroll")                                                \
      for (int mi = 0; mi < 2; ++mi)                                   \
        af[mi] = *(const bf16x8*)&As[BUF][wm + (mi << 4) + fr][(kk << 5) + fk]; \
      _Pragma("unroll")                                                \
      for (int ni = 0; ni < 2; ++ni)                                   \
        bff[ni] = *(const bf16x8*)&Bs[BUF][wn + (ni << 4) + fr][(kk << 5) + fk]; \
      _Pragma("unroll")                                                \
      for (int mi = 0; mi < 2; ++mi)                                   \
        _Pragma("unroll")                                              \
        for (int ni = 0; ni < 2; ++ni)                                 \
          acc[mi][ni] = __builtin_amdgcn_mfma_f32_16x16x32_bf16(       \
              af[mi], bff[ni], acc[mi][ni], 0, 0, 0);                  \
    }                                                                  \
  }

  LDCHUNK(0)
  STCHUNK(0)
  __syncthreads();
  LDCHUNK(64) COMPUTE(0) STCHUNK(1) __syncthreads();
  LDCHUNK(128) COMPUTE(1) STCHUNK(0) __syncthreads();
  LDCHUNK(192) COMPUTE(0) STCHUNK(1) __syncthreads();
  COMPUTE(1)

  const float SC = 2.8853900817779268f;  // 2*log2(e)
#pragma unroll
  for (int mi = 0; mi < 2; ++mi) {
#pragma unroll
    for (int ni = 0; ni < 2; ++ni) {
      const int row = m0 + wm + (mi << 4) + ((lane >> 4) << 2);
      const int col = n0 + wn + (ni << 4) + (lane & 15);
#pragma unroll
      for (int r = 0; r < 4; ++r) {
        const float val = __builtin_amdgcn_exp2f(acc[mi][ni][r] * SC);
        if (decside) {
          // interleaved: [(d>>1)][h][d&1]
          const int rr = row + r;
          C[((size_t)(rr >> 1) * H_ + col) * 2 + (rr & 1)] = val;
        } else {
          C[(size_t)(row + r) * ldc + col] = val;
        }
      }
    }
  }
}

// ---------------- Kernel 2a: raw scores (h-major LDS, forced VOP3P) ----------------
// Block = 1024 thr = 16 waves, covers 64 e x 32 d. Es = [h(256)][e(64)] fp32
// (64KB): lane l reads &Es[h*64 + l] -> 64 consecutive lanes, conflict-free
// ds_read_b32 with imm offsets. Staging = direct copy (no transpose).
// E operand = f2 {E_h, E_h+1} from two b32 reads (op_sel lo/hi). dq/w = SGPR
// pairs via uniform s_loads. Writes raw -2*acc. Grid 512 -> 2 blk/CU.

__global__ __launch_bounds__(1024) void scores_k(
    const float* __restrict__ encE, const float* __restrict__ decEi,
    const float* __restrict__ v, float* __restrict__ out) {
  const int bid = blockIdx.x;            // 0..511
  // XCD pinning: batch b -> XCDs {2b, 2b+1}
  const int xcd = bid & 7;
  const int b = xcd >> 1;
  const int rem = ((bid >> 3) << 1) | (xcd & 1);   // 0..127 within batch
  const int es = rem & 15;               // e-slice (64 e)
  const int d0 = (rem >> 4) << 5;        // d-group of 32
  const int tid = threadIdx.x;
  const int lane = tid & 63;
  const int wid = __builtin_amdgcn_readfirstlane(tid >> 6);  // 0..15

  __shared__ __align__(16) float Es[H_ * 64];    // [h][e] h-major, 64KB

  const int e0 = es << 6;
  const float* egbase = encE + (size_t)b * H_ * ENC_ + e0;

  // ---- stage (direct copy): 4 x {float4 load + ds_write_b128} / thread ----
#pragma unroll
  for (int s = 0; s < 4; ++s) {
    const int fi = (s << 10) + tid;      // 0..4095
    const int h = fi >> 4;               // 0..255
    const int c = fi & 15;               // float4 chunk along e
    const float4 x = *(const float4*)(egbase + (size_t)h * ENC_ + (c << 2));
    *(float4*)&Es[(h << 6) + (c << 2)] = x;
  }
  __syncthreads();

  const int dpair = (d0 >> 1) + wid;     // d = 2*dpair, 2*dpair+1
  const float* dpi = decEi + (size_t)b * DEC_ * H_ + (size_t)dpair * (2 * H_);
  const float* epl = Es + lane;

  f2 acc = {0.0f, 0.0f};
  const f2 one2 = {1.0f, 1.0f};

#pragma unroll 4
  for (int g = 0; g < 64; ++g) {
    // conflict-free b32 reads; pack adjacent h into register pairs
    f2 E01, E23;
    E01.x = epl[(4 * g + 0) << 6];
    E01.y = epl[(4 * g + 1) << 6];
    E23.x = epl[(4 * g + 2) << 6];
    E23.y = epl[(4 * g + 3) << 6];
    const f2 dq0 = *(const f2*)(dpi + (g << 3));   // uniform -> SGPR pairs
    const f2 dq1 = *(const f2*)(dpi + (g << 3) + 2);
    const f2 dq2 = *(const f2*)(dpi + (g << 3) + 4);
    const f2 dq3 = *(const f2*)(dpi + (g << 3) + 6);
    const f2 w01 = *(const f2*)(v + (g << 2));     // uniform -> SGPR pair
    const f2 w23 = *(const f2*)(v + (g << 2) + 2);

    const f2 m0 = pk_fma_dq_elo(dq0, E01, one2);   // {1+E0*dA0, 1+E0*dB0}
    const f2 m1 = pk_fma_dq_ehi(dq1, E01, one2);
    const f2 m2 = pk_fma_dq_elo(dq2, E23, one2);
    const f2 m3 = pk_fma_dq_ehi(dq3, E23, one2);
    const f2 pa = pk_mul(m0, m1);
    const f2 pb = pk_mul(m2, m3);
    const f2 n01 = pk_fma_whi(w01, m0, pk_mul_wlo(w01, m1));
    const f2 n23 = pk_fma_whi(w23, m2, pk_mul_wlo(w23, m3));
    const f2 num = pk_fma(n01, pb, pk_mul(n23, pa));
    const f2 den = pk_mul(pa, pb);
    f2 r;
    r.x = __builtin_amdgcn_rcpf(den.x);
    r.y = __builtin_amdgcn_rcpf(den.y);
    acc = pk_fma(num, r, acc);
  }

  const int d = dpair << 1;
  float* orow = out + (size_t)(b * DEC_ + d) * ENC_ + e0 + lane;
  orow[0] = -2.0f * acc.x;
  orow[ENC_] = -2.0f * acc.y;
}

// ---------------- Kernel 2b: in-place row log_softmax ----------------
// 1 row (1024 f32) per block, 256 thr x float4.

__global__ __launch_bounds__(256) void lsm_k(float* __restrict__ out) {
  const int row = blockIdx.x;            // 0..1023
  float* p = out + (size_t)row * ENC_;
  const int tid = threadIdx.x;
  const int lane = tid & 63, wid = tid >> 6;

  __shared__ float rm[4], rs[4];

  float4 x = *(const float4*)(p + 4 * tid);

  float m = fmaxf(fmaxf(x.x, x.y), fmaxf(x.z, x.w));
#pragma unroll
  for (int o = 32; o >= 1; o >>= 1) m = fmaxf(m, __shfl_xor(m, o, 64));
  if (lane == 0) rm[wid] = m;
  __syncthreads();
  const float M = fmaxf(fmaxf(rm[0], rm[1]), fmaxf(rm[2], rm[3]));

  const float L2E = 1.4426950408889634f;
  const float LN2 = 0.6931471805599453f;
  float z = __builtin_amdgcn_exp2f((x.x - M) * L2E) +
            __builtin_amdgcn_exp2f((x.y - M) * L2E) +
            __builtin_amdgcn_exp2f((x.z - M) * L2E) +
            __builtin_amdgcn_exp2f((x.w - M) * L2E);
#pragma unroll
  for (int o = 32; o >= 1; o >>= 1) z += __shfl_xor(z, o, 64);
  if (lane == 0) rs[wid] = z;
  __syncthreads();
  const float S = (rs[0] + rs[1]) + (rs[2] + rs[3]);

  const float lse = M + LN2 * __builtin_amdgcn_logf(S);
  x.x -= lse; x.y -= lse; x.z -= lse; x.w -= lse;
  *(float4*)(p + 4 * tid) = x;
}

extern "C" void kernel_launch(void* const* d_in, const int* in_sizes, int n_in,
                              void* d_out, int out_size, void* d_ws, size_t ws_size,
                              hipStream_t stream) {
  const float* xd = (const float*)d_in[0];  // (4,256,256)
  const float* xe = (const float*)d_in[1];  // (4,1024,256)
  const float* w1 = (const float*)d_in[2];  // (256,256)
  const float* w2 = (const float*)d_in[3];  // (256,256)
  const float* v  = (const float*)d_in[4];  // (256,)
  float* out = (float*)d_out;               // (4,256,1024)

  float* encE = (float*)d_ws;                          // 4 MB: [B][H][ENC]
  float* decEi = encE + (size_t)B_ * H_ * ENC_;        // 1 MB: [B][dpair][H][2]

  gemm_mfma<<<320, 256, 0, stream>>>(w1, xe, xd, w2, encE, decEi);
  scores_k<<<512, 1024, 0, stream>>>(encE, decEi, v, out);
  lsm_k<<<B_ * DEC_, 256, 0, stream>>>(out);
}